// Round 1
// baseline (1415.428 us; speedup 1.0000x reference)
//
#include <hip/hip_runtime.h>
#include <stdint.h>

#define B_ 4
#define T_ 1024
#define C_ 2048
#define H_ 32
#define HKV_ 8
#define HD_ 64
#define HID_ 5632

typedef __attribute__((ext_vector_type(8))) short short8;
typedef __attribute__((ext_vector_type(4))) float floatx4;

__device__ __forceinline__ float b2f(short s) {
  unsigned u = ((unsigned)(unsigned short)s) << 16;
  return __uint_as_float(u);
}
__device__ __forceinline__ short f2b(float f) {
  unsigned u = __float_as_uint(f);
  u = u + 0x7fffu + ((u >> 16) & 1u);
  return (short)(u >> 16);
}

// ---------------- RMSNorm: fp32 row -> bf16 row ----------------
__global__ __launch_bounds__(256) void rmsnorm_kernel(
    const float* __restrict__ x, const float* __restrict__ scale,
    short* __restrict__ out) {
  int row = blockIdx.x, tid = threadIdx.x;
  const float4* xr = (const float4*)(x + (size_t)row * C_);
  float4 v0 = xr[tid], v1 = xr[tid + 256];
  float s = v0.x * v0.x + v0.y * v0.y + v0.z * v0.z + v0.w * v0.w +
            v1.x * v1.x + v1.y * v1.y + v1.z * v1.z + v1.w * v1.w;
  for (int off = 32; off > 0; off >>= 1) s += __shfl_down(s, off, 64);
  __shared__ float red[4];
  if ((tid & 63) == 0) red[tid >> 6] = s;
  __syncthreads();
  float tot = red[0] + red[1] + red[2] + red[3];
  float r = rsqrtf(tot * (1.0f / (float)C_) + 1e-6f);
  const float4* sc = (const float4*)scale;
  float4 s0 = sc[tid], s1 = sc[tid + 256];
  short* o = out + (size_t)row * C_;
  o[tid * 4 + 0] = f2b(v0.x * s0.x * r);
  o[tid * 4 + 1] = f2b(v0.y * s0.y * r);
  o[tid * 4 + 2] = f2b(v0.z * s0.z * r);
  o[tid * 4 + 3] = f2b(v0.w * s0.w * r);
  o[1024 + tid * 4 + 0] = f2b(v1.x * s1.x * r);
  o[1024 + tid * 4 + 1] = f2b(v1.y * s1.y * r);
  o[1024 + tid * 4 + 2] = f2b(v1.z * s1.z * r);
  o[1024 + tid * 4 + 3] = f2b(v1.w * s1.w * r);
}

// ---------------- GEMM: A[M,K] bf16 @ Bw[K,N] fp32 -> epilogue ----------------
// EPI 0: store bf16.  EPI 1: fp32 store = resid + acc.  EPI 2: bf16 store = silu(gate)*acc.
template <int EPI>
__global__ __launch_bounds__(256) void gemm_kernel(
    const short* __restrict__ A, const float* __restrict__ Bw,
    void* __restrict__ Out, const float* __restrict__ resid,
    const short* __restrict__ gate, int M, int N, int K) {
  __shared__ __align__(16) short As[64 * 40];
  __shared__ __align__(16) short Bs[64 * 40];  // transposed: Bs[n][k]
  int tid = threadIdx.x;
  int m0 = blockIdx.y * 64, n0 = blockIdx.x * 64;
  int lane = tid & 63, wave = tid >> 6;
  int quad = lane >> 4, l16 = lane & 15;
  int wm = (wave & 1) * 32, wn = (wave >> 1) * 32;
  int arow = tid >> 2, acol = (tid & 3) * 8;  // A stage: 8 contiguous k per thread
  int bn = tid & 63, bk = (tid >> 6) * 8;     // B stage: 8 k rows per thread, coalesced in n
  floatx4 acc[2][2] = {};
  const short* aptr = A + (size_t)(m0 + arow) * K + acol;
  const float* bptr = Bw + (size_t)bk * N + n0 + bn;
  for (int k0 = 0; k0 < K; k0 += 32) {
    int4 araw = *(const int4*)(aptr + k0);
    float bfv[8];
#pragma unroll
    for (int j = 0; j < 8; ++j) bfv[j] = bptr[(size_t)(k0 + j) * N];
    short8 bp;
#pragma unroll
    for (int j = 0; j < 8; ++j) bp[j] = f2b(bfv[j]);
    *(int4*)(&As[arow * 40 + acol]) = araw;
    *(short8*)(&Bs[bn * 40 + bk]) = bp;
    __syncthreads();
    short8 a0 = *(const short8*)(&As[(wm + l16) * 40 + quad * 8]);
    short8 a1 = *(const short8*)(&As[(wm + 16 + l16) * 40 + quad * 8]);
    short8 b0 = *(const short8*)(&Bs[(wn + l16) * 40 + quad * 8]);
    short8 b1 = *(const short8*)(&Bs[(wn + 16 + l16) * 40 + quad * 8]);
    acc[0][0] = __builtin_amdgcn_mfma_f32_16x16x32_bf16(a0, b0, acc[0][0], 0, 0, 0);
    acc[0][1] = __builtin_amdgcn_mfma_f32_16x16x32_bf16(a0, b1, acc[0][1], 0, 0, 0);
    acc[1][0] = __builtin_amdgcn_mfma_f32_16x16x32_bf16(a1, b0, acc[1][0], 0, 0, 0);
    acc[1][1] = __builtin_amdgcn_mfma_f32_16x16x32_bf16(a1, b1, acc[1][1], 0, 0, 0);
    __syncthreads();
  }
#pragma unroll
  for (int mi = 0; mi < 2; ++mi)
#pragma unroll
    for (int ni = 0; ni < 2; ++ni)
#pragma unroll
      for (int r = 0; r < 4; ++r) {
        int row = m0 + wm + mi * 16 + quad * 4 + r;
        int col = n0 + wn + ni * 16 + l16;
        float a = acc[mi][ni][r];
        size_t idx = (size_t)row * N + col;
        if constexpr (EPI == 0) {
          ((short*)Out)[idx] = f2b(a);
        } else if constexpr (EPI == 1) {
          ((float*)Out)[idx] = resid[idx] + a;
        } else {
          float gg = b2f(gate[idx]);
          ((short*)Out)[idx] = f2b(a * gg / (1.0f + __expf(-gg)));
        }
      }
}

// ---------------- RoPE + QKV split ----------------
__global__ __launch_bounds__(256) void rope_kernel(
    const short* __restrict__ qkv, const float* __restrict__ cosp,
    const float* __restrict__ sinp, short* __restrict__ q,
    short* __restrict__ k, short* __restrict__ v) {
  int idx = blockIdx.x * 256 + threadIdx.x;  // (b,t,head,i)
  int i = idx & 31;
  int rest = idx >> 5;
  int head = rest % 48;
  int rest2 = rest / 48;
  int t = rest2 & 1023;
  int b = rest2 >> 10;
  const short* src = qkv + (size_t)(b * T_ + t) * 3072 + head * 64 + 2 * i;
  float e = b2f(src[0]), o = b2f(src[1]);
  if (head < 32) {
    float c = cosp[t * 32 + i], s = sinp[t * 32 + i];
    short* dst = q + ((size_t)(b * 32 + head) * 1024 + t) * 64 + 2 * i;
    dst[0] = f2b(e * c - o * s);
    dst[1] = f2b(e * s + o * c);
  } else if (head < 40) {
    float c = cosp[t * 32 + i], s = sinp[t * 32 + i];
    short* dst = k + ((size_t)(b * 8 + (head - 32)) * 1024 + t) * 64 + 2 * i;
    dst[0] = f2b(e * c - o * s);
    dst[1] = f2b(e * s + o * c);
  } else {
    short* dst = v + ((size_t)(b * 8 + (head - 40)) * 1024 + t) * 64 + 2 * i;
    dst[0] = src[0];
    dst[1] = src[1];
  }
}

// ---------------- Flash attention (GQA, causal) ----------------
// One block = 64 q rows (4 waves x 16). Per-wave online softmax, P via wave-local LDS.
__global__ __launch_bounds__(256) void attn_kernel(
    const short* __restrict__ q, const short* __restrict__ k,
    const short* __restrict__ v, short* __restrict__ y) {
  __shared__ __align__(16) short P[4][640];  // per-wave 16x(32+pad8), stride 40
  int bx = blockIdx.x, h = blockIdx.y, b = blockIdx.z;
  int lane = threadIdx.x & 63, wave = threadIdx.x >> 6;
  int quad = lane >> 4, l16 = lane & 15;
  int g = h >> 2;
  const short* qp = q + (size_t)(b * H_ + h) * T_ * HD_;
  const short* kp = k + (size_t)(b * HKV_ + g) * T_ * HD_;
  const short* vp = v + (size_t)(b * HKV_ + g) * T_ * HD_;
  int q0 = bx * 64 + wave * 16;
  short8 qf0 = *(const short8*)(qp + (q0 + l16) * HD_ + quad * 8);
  short8 qf1 = *(const short8*)(qp + (q0 + l16) * HD_ + 32 + quad * 8);
  floatx4 acc[4] = {};
  float m_r[4] = {-1e30f, -1e30f, -1e30f, -1e30f};
  float l_r[4] = {0.f, 0.f, 0.f, 0.f};
  int qi[4];
#pragma unroll
  for (int r = 0; r < 4; ++r) qi[r] = q0 + quad * 4 + r;
  for (int k0 = 0; k0 < q0 + 16; k0 += 32) {
    floatx4 s0 = {0.f, 0.f, 0.f, 0.f}, s1 = {0.f, 0.f, 0.f, 0.f};
    short8 kf0 = *(const short8*)(kp + (k0 + l16) * HD_ + quad * 8);
    short8 kf0b = *(const short8*)(kp + (k0 + l16) * HD_ + 32 + quad * 8);
    s0 = __builtin_amdgcn_mfma_f32_16x16x32_bf16(qf0, kf0, s0, 0, 0, 0);
    s0 = __builtin_amdgcn_mfma_f32_16x16x32_bf16(qf1, kf0b, s0, 0, 0, 0);
    short8 kf1 = *(const short8*)(kp + (k0 + 16 + l16) * HD_ + quad * 8);
    short8 kf1b = *(const short8*)(kp + (k0 + 16 + l16) * HD_ + 32 + quad * 8);
    s1 = __builtin_amdgcn_mfma_f32_16x16x32_bf16(qf0, kf1, s1, 0, 0, 0);
    s1 = __builtin_amdgcn_mfma_f32_16x16x32_bf16(qf1, kf1b, s1, 0, 0, 0);
    float p0[4], p1[4], mt[4];
#pragma unroll
    for (int r = 0; r < 4; ++r) {
      p0[r] = (k0 + l16 <= qi[r]) ? s0[r] * 0.125f : -1e30f;
      p1[r] = (k0 + 16 + l16 <= qi[r]) ? s1[r] * 0.125f : -1e30f;
      mt[r] = fmaxf(p0[r], p1[r]);
    }
#pragma unroll
    for (int off = 1; off < 16; off <<= 1) {
#pragma unroll
      for (int r = 0; r < 4; ++r) mt[r] = fmaxf(mt[r], __shfl_xor(mt[r], off, 64));
    }
    float alpha[4];
#pragma unroll
    for (int r = 0; r < 4; ++r) {
      float mn = fmaxf(m_r[r], mt[r]);
      alpha[r] = __expf(m_r[r] - mn);
      m_r[r] = mn;
      p0[r] = __expf(p0[r] - mn);
      p1[r] = __expf(p1[r] - mn);
    }
    float rs[4];
#pragma unroll
    for (int r = 0; r < 4; ++r) rs[r] = p0[r] + p1[r];
#pragma unroll
    for (int off = 1; off < 16; off <<= 1) {
#pragma unroll
      for (int r = 0; r < 4; ++r) rs[r] += __shfl_xor(rs[r], off, 64);
    }
#pragma unroll
    for (int r = 0; r < 4; ++r) l_r[r] = l_r[r] * alpha[r] + rs[r];
#pragma unroll
    for (int n = 0; n < 4; ++n)
#pragma unroll
      for (int r = 0; r < 4; ++r) acc[n][r] *= alpha[r];
#pragma unroll
    for (int r = 0; r < 4; ++r) {
      P[wave][(quad * 4 + r) * 40 + l16] = f2b(p0[r]);
      P[wave][(quad * 4 + r) * 40 + 16 + l16] = f2b(p1[r]);
    }
    short8 pf = *(const short8*)(&P[wave][l16 * 40 + quad * 8]);
#pragma unroll
    for (int n = 0; n < 4; ++n) {
      short8 vf;
#pragma unroll
      for (int j = 0; j < 8; ++j)
        vf[j] = vp[(size_t)(k0 + quad * 8 + j) * HD_ + n * 16 + l16];
      acc[n] = __builtin_amdgcn_mfma_f32_16x16x32_bf16(pf, vf, acc[n], 0, 0, 0);
    }
  }
#pragma unroll
  for (int n = 0; n < 4; ++n)
#pragma unroll
    for (int r = 0; r < 4; ++r) {
      int t = q0 + quad * 4 + r;
      y[(size_t)(b * T_ + t) * C_ + h * 64 + n * 16 + l16] = f2b(acc[n][r] / l_r[r]);
    }
}

extern "C" void kernel_launch(void* const* d_in, const int* in_sizes, int n_in,
                              void* d_out, int out_size, void* d_ws, size_t ws_size,
                              hipStream_t stream) {
  const float* x = (const float*)d_in[0];
  const float* cosp = (const float*)d_in[1];
  const float* sinp = (const float*)d_in[2];
  const float* w_attn = (const float*)d_in[3];
  const float* w_proj = (const float*)d_in[4];
  const float* w_gate = (const float*)d_in[5];
  const float* w_up = (const float*)d_in[6];
  const float* w_down = (const float*)d_in[7];
  const float* scale1 = (const float*)d_in[8];
  const float* scale2 = (const float*)d_in[9];
  float* out = (float*)d_out;
  char* ws = (char*)d_ws;

  // workspace layout (bytes); peak use ~113.3 MB with phase-based reuse
  short* h = (short*)(ws + 0);                    // 16.78 MB  (h, later h2)
  short* qkv = (short*)(ws + 16777216);           // 25.17 MB
  short* g = (short*)(ws + 16777216);             // 46.14 MB (after attn; over dead qkv/q/k)
  short* qb = (short*)(ws + 41943040);            // 16.78 MB
  short* kb = (short*)(ws + 58720256);            //  4.19 MB
  short* vb = (short*)(ws + 62914560);            //  4.19 MB
  short* y = (short*)(ws + 67108864);             // 16.78 MB
  short* act = (short*)(ws + 67108864);           // 46.14 MB (after proj; over dead y)

  rmsnorm_kernel<<<4096, 256, 0, stream>>>(x, scale1, h);
  gemm_kernel<0><<<dim3(3072 / 64, 4096 / 64), 256, 0, stream>>>(
      h, w_attn, qkv, nullptr, nullptr, 4096, 3072, 2048);
  rope_kernel<<<24576, 256, 0, stream>>>(qkv, cosp, sinp, qb, kb, vb);
  attn_kernel<<<dim3(16, 32, 4), 256, 0, stream>>>(qb, kb, vb, y);
  gemm_kernel<1><<<dim3(2048 / 64, 4096 / 64), 256, 0, stream>>>(
      y, w_proj, out, x, nullptr, 4096, 2048, 2048);
  rmsnorm_kernel<<<4096, 256, 0, stream>>>(out, scale2, h);
  gemm_kernel<0><<<dim3(5632 / 64, 4096 / 64), 256, 0, stream>>>(
      h, w_gate, g, nullptr, nullptr, 4096, 5632, 2048);
  gemm_kernel<2><<<dim3(5632 / 64, 4096 / 64), 256, 0, stream>>>(
      h, w_up, act, nullptr, g, 4096, 5632, 2048);
  gemm_kernel<1><<<dim3(2048 / 64, 4096 / 64), 256, 0, stream>>>(
      act, w_down, out, out, nullptr, 4096, 2048, 5632);
}

// Round 2
// 901.882 us; speedup vs baseline: 1.5694x; 1.5694x over previous
//
#include <hip/hip_runtime.h>
#include <stdint.h>

#define B_ 4
#define T_ 1024
#define C_ 2048
#define H_ 32
#define HKV_ 8
#define HD_ 64
#define HID_ 5632

typedef __attribute__((ext_vector_type(8))) short short8;
typedef __attribute__((ext_vector_type(4))) float floatx4;

__device__ __forceinline__ float b2f(short s) {
  unsigned u = ((unsigned)(unsigned short)s) << 16;
  return __uint_as_float(u);
}
__device__ __forceinline__ short f2b(float f) {
  unsigned u = __float_as_uint(f);
  u = u + 0x7fffu + ((u >> 16) & 1u);
  return (short)(u >> 16);
}

// async global->LDS, 16B per lane, LDS dest = wave-uniform base + lane*16
#define GL2LDS(gp, lp)                                              \
  __builtin_amdgcn_global_load_lds(                                 \
      (const __attribute__((address_space(1))) void*)(gp),          \
      (__attribute__((address_space(3))) void*)(lp), 16, 0, 0)

// ---------------- weight convert + transpose: W[K][N] fp32 -> Wt[N][K] bf16 ----
__global__ __launch_bounds__(256) void convt_kernel(
    const float* __restrict__ W, short* __restrict__ Wt, int K, int N) {
  __shared__ short t[32][33];
  int n0 = blockIdx.x * 32, k0 = blockIdx.y * 32;
  int tx = threadIdx.x & 31, ty = threadIdx.x >> 5;  // ty 0..7
#pragma unroll
  for (int j = 0; j < 4; ++j)
    t[ty + j * 8][tx] = f2b(W[(size_t)(k0 + ty + j * 8) * N + n0 + tx]);
  __syncthreads();
#pragma unroll
  for (int j = 0; j < 4; ++j)
    Wt[(size_t)(n0 + ty + j * 8) * K + k0 + tx] = t[tx][ty + j * 8];
}

// ---------------- RMSNorm: fp32 row -> bf16 row ----------------
__global__ __launch_bounds__(256) void rmsnorm_kernel(
    const float* __restrict__ x, const float* __restrict__ scale,
    short* __restrict__ out) {
  int row = blockIdx.x, tid = threadIdx.x;
  const float4* xr = (const float4*)(x + (size_t)row * C_);
  float4 v0 = xr[tid], v1 = xr[tid + 256];
  float s = v0.x * v0.x + v0.y * v0.y + v0.z * v0.z + v0.w * v0.w +
            v1.x * v1.x + v1.y * v1.y + v1.z * v1.z + v1.w * v1.w;
  for (int off = 32; off > 0; off >>= 1) s += __shfl_down(s, off, 64);
  __shared__ float red[4];
  if ((tid & 63) == 0) red[tid >> 6] = s;
  __syncthreads();
  float tot = red[0] + red[1] + red[2] + red[3];
  float r = rsqrtf(tot * (1.0f / (float)C_) + 1e-6f);
  const float4* sc = (const float4*)scale;
  float4 s0 = sc[tid], s1 = sc[tid + 256];
  short* o = out + (size_t)row * C_;
  o[tid * 4 + 0] = f2b(v0.x * s0.x * r);
  o[tid * 4 + 1] = f2b(v0.y * s0.y * r);
  o[tid * 4 + 2] = f2b(v0.z * s0.z * r);
  o[tid * 4 + 3] = f2b(v0.w * s0.w * r);
  o[1024 + tid * 4 + 0] = f2b(v1.x * s1.x * r);
  o[1024 + tid * 4 + 1] = f2b(v1.y * s1.y * r);
  o[1024 + tid * 4 + 2] = f2b(v1.z * s1.z * r);
  o[1024 + tid * 4 + 3] = f2b(v1.w * s1.w * r);
}

// ---------------- GEMM 128x128, BK=32, m97 structure -------------------------
// A[M][K] bf16 row-major, Bt[N][K] bf16 row-major (pre-transposed weights).
// LDS: 16B chunks, slot(row,kc) = row*4 + ((kc + (row>>1)) & 3)  (bank-swizzle).
// EPI 0: bf16 store.  EPI 1: fp32 store = resid + acc.
template <int EPI>
__global__ __launch_bounds__(256, 2) void gemm128_kernel(
    const short* __restrict__ A, const short* __restrict__ Bt,
    void* __restrict__ Out, const float* __restrict__ resid,
    int M, int N, int K) {
  __shared__ __align__(16) short smem[8192];
  short* As = smem;         // 512 slots * 16B
  short* Bs = smem + 4096;
  int tid = threadIdx.x, lane = tid & 63, wave = tid >> 6;
  int quad = lane >> 4, l16 = lane & 15;
  int m0 = blockIdx.y * 128, n0 = blockIdx.x * 128;
  int wm = (wave & 1) * 64, wn = (wave >> 1) * 64;

  // staging: wave handles slots [wave*128, wave*128+128), 2 calls of 64
  int SA0 = wave * 128 + lane, SA1 = SA0 + 64;
  int rA0 = SA0 >> 2, kA0 = ((SA0 & 3) - ((SA0 >> 3) & 3)) & 3;
  int rA1 = SA1 >> 2, kA1 = ((SA1 & 3) - ((SA1 >> 3) & 3)) & 3;
  const short* ap0 = A + (size_t)(m0 + rA0) * K + kA0 * 8;
  const short* ap1 = A + (size_t)(m0 + rA1) * K + kA1 * 8;
  const short* bp0 = Bt + (size_t)(n0 + rA0) * K + kA0 * 8;
  const short* bp1 = Bt + (size_t)(n0 + rA1) * K + kA1 * 8;
  short* lA0 = As + (wave * 128) * 8;
  short* lA1 = As + (wave * 128 + 64) * 8;
  short* lB0 = Bs + (wave * 128) * 8;
  short* lB1 = Bs + (wave * 128 + 64) * 8;

  int aoff[4], boff[4];
#pragma unroll
  for (int i = 0; i < 4; ++i) {
    int ra = wm + i * 16 + l16;
    aoff[i] = (ra * 4 + ((quad + (ra >> 1)) & 3)) * 8;
    int rb = wn + i * 16 + l16;
    boff[i] = (rb * 4 + ((quad + (rb >> 1)) & 3)) * 8;
  }

  floatx4 acc[4][4] = {};
  for (int k0 = 0; k0 < K; k0 += 32) {
    GL2LDS(ap0 + k0, lA0);
    GL2LDS(ap1 + k0, lA1);
    GL2LDS(bp0 + k0, lB0);
    GL2LDS(bp1 + k0, lB1);
    __syncthreads();
    short8 af[4], bf[4];
#pragma unroll
    for (int i = 0; i < 4; ++i) af[i] = *(const short8*)(As + aoff[i]);
#pragma unroll
    for (int i = 0; i < 4; ++i) bf[i] = *(const short8*)(Bs + boff[i]);
#pragma unroll
    for (int mi = 0; mi < 4; ++mi)
#pragma unroll
      for (int ni = 0; ni < 4; ++ni)
        acc[mi][ni] = __builtin_amdgcn_mfma_f32_16x16x32_bf16(
            af[mi], bf[ni], acc[mi][ni], 0, 0, 0);
    __syncthreads();
  }
#pragma unroll
  for (int mi = 0; mi < 4; ++mi)
#pragma unroll
    for (int ni = 0; ni < 4; ++ni)
#pragma unroll
      for (int r = 0; r < 4; ++r) {
        int row = m0 + wm + mi * 16 + quad * 4 + r;
        int col = n0 + wn + ni * 16 + l16;
        size_t idx = (size_t)row * N + col;
        float a = acc[mi][ni][r];
        if constexpr (EPI == 0)
          ((short*)Out)[idx] = f2b(a);
        else
          ((float*)Out)[idx] = resid[idx] + a;
      }
}

// ---------------- fused gate+up GEMM with silu-mul epilogue -------------------
// Block: 128 M-rows x 64 N-cols of BOTH gate and up. B-tile rows 0..63 = Wg,
// 64..127 = Wu. Waves: wm=(w&1)*64, half=w>>1 (0=gate,1=up). act = silu(g)*u.
__global__ __launch_bounds__(256, 2) void gateup_kernel(
    const short* __restrict__ A, const short* __restrict__ Wg,
    const short* __restrict__ Wu, short* __restrict__ act, int K) {
  __shared__ __align__(16) short smem[8192];
  short* As = smem;
  short* Bs = smem + 4096;
  int tid = threadIdx.x, lane = tid & 63, wave = tid >> 6;
  int quad = lane >> 4, l16 = lane & 15;
  int m0 = blockIdx.y * 128, n0 = blockIdx.x * 64;
  int wm = (wave & 1) * 64, half = wave >> 1;

  int SA0 = wave * 128 + lane, SA1 = SA0 + 64;
  int rA0 = SA0 >> 2, kA0 = ((SA0 & 3) - ((SA0 >> 3) & 3)) & 3;
  int rA1 = SA1 >> 2, kA1 = ((SA1 & 3) - ((SA1 >> 3) & 3)) & 3;
  const short* ap0 = A + (size_t)(m0 + rA0) * K + kA0 * 8;
  const short* ap1 = A + (size_t)(m0 + rA1) * K + kA1 * 8;
  const short* bp0 = (rA0 < 64 ? Wg + (size_t)(n0 + rA0) * K
                               : Wu + (size_t)(n0 + rA0 - 64) * K) + kA0 * 8;
  const short* bp1 = (rA1 < 64 ? Wg + (size_t)(n0 + rA1) * K
                               : Wu + (size_t)(n0 + rA1 - 64) * K) + kA1 * 8;
  short* lA0 = As + (wave * 128) * 8;
  short* lA1 = As + (wave * 128 + 64) * 8;
  short* lB0 = Bs + (wave * 128) * 8;
  short* lB1 = Bs + (wave * 128 + 64) * 8;

  int aoff[4], boff[4];
#pragma unroll
  for (int i = 0; i < 4; ++i) {
    int ra = wm + i * 16 + l16;
    aoff[i] = (ra * 4 + ((quad + (ra >> 1)) & 3)) * 8;
    int rb = half * 64 + i * 16 + l16;
    boff[i] = (rb * 4 + ((quad + (rb >> 1)) & 3)) * 8;
  }

  floatx4 acc[4][4] = {};
  for (int k0 = 0; k0 < K; k0 += 32) {
    GL2LDS(ap0 + k0, lA0);
    GL2LDS(ap1 + k0, lA1);
    GL2LDS(bp0 + k0, lB0);
    GL2LDS(bp1 + k0, lB1);
    __syncthreads();
    short8 af[4], bf[4];
#pragma unroll
    for (int i = 0; i < 4; ++i) af[i] = *(const short8*)(As + aoff[i]);
#pragma unroll
    for (int i = 0; i < 4; ++i) bf[i] = *(const short8*)(Bs + boff[i]);
#pragma unroll
    for (int mi = 0; mi < 4; ++mi)
#pragma unroll
      for (int ni = 0; ni < 4; ++ni)
        acc[mi][ni] = __builtin_amdgcn_mfma_f32_16x16x32_bf16(
            af[mi], bf[ni], acc[mi][ni], 0, 0, 0);
    __syncthreads();
  }
  // epilogue: up waves deposit u (bf16) in LDS [128][64], gate waves combine
  short* Ex = smem;  // 8192 shorts = 128*64
  if (half == 1) {
#pragma unroll
    for (int mi = 0; mi < 4; ++mi)
#pragma unroll
      for (int ni = 0; ni < 4; ++ni)
#pragma unroll
        for (int r = 0; r < 4; ++r)
          Ex[(wm + mi * 16 + quad * 4 + r) * 64 + ni * 16 + l16] =
              f2b(acc[mi][ni][r]);
  }
  __syncthreads();
  if (half == 0) {
#pragma unroll
    for (int mi = 0; mi < 4; ++mi)
#pragma unroll
      for (int ni = 0; ni < 4; ++ni)
#pragma unroll
        for (int r = 0; r < 4; ++r) {
          int row = wm + mi * 16 + quad * 4 + r;
          int col = ni * 16 + l16;
          float u = b2f(Ex[row * 64 + col]);
          float g = acc[mi][ni][r];
          float a = g / (1.0f + __expf(-g)) * u;
          act[(size_t)(m0 + row) * HID_ + n0 + col] = f2b(a);
        }
  }
}

// ---------------- RoPE + QKV split ----------------
__global__ __launch_bounds__(256) void rope_kernel(
    const short* __restrict__ qkv, const float* __restrict__ cosp,
    const float* __restrict__ sinp, short* __restrict__ q,
    short* __restrict__ k, short* __restrict__ v) {
  int idx = blockIdx.x * 256 + threadIdx.x;  // (b,t,head,i)
  int i = idx & 31;
  int rest = idx >> 5;
  int head = rest % 48;
  int rest2 = rest / 48;
  int t = rest2 & 1023;
  int b = rest2 >> 10;
  const short* src = qkv + (size_t)(b * T_ + t) * 3072 + head * 64 + 2 * i;
  float e = b2f(src[0]), o = b2f(src[1]);
  if (head < 32) {
    float c = cosp[t * 32 + i], s = sinp[t * 32 + i];
    short* dst = q + ((size_t)(b * 32 + head) * 1024 + t) * 64 + 2 * i;
    dst[0] = f2b(e * c - o * s);
    dst[1] = f2b(e * s + o * c);
  } else if (head < 40) {
    float c = cosp[t * 32 + i], s = sinp[t * 32 + i];
    short* dst = k + ((size_t)(b * 8 + (head - 32)) * 1024 + t) * 64 + 2 * i;
    dst[0] = f2b(e * c - o * s);
    dst[1] = f2b(e * s + o * c);
  } else {
    short* dst = v + ((size_t)(b * 8 + (head - 40)) * 1024 + t) * 64 + 2 * i;
    dst[0] = src[0];
    dst[1] = src[1];
  }
}

// ---------------- Flash attention (GQA, causal) ----------------
__global__ __launch_bounds__(256) void attn_kernel(
    const short* __restrict__ q, const short* __restrict__ k,
    const short* __restrict__ v, short* __restrict__ y) {
  __shared__ __align__(16) short P[4][640];
  int bx = blockIdx.x, h = blockIdx.y, b = blockIdx.z;
  int lane = threadIdx.x & 63, wave = threadIdx.x >> 6;
  int quad = lane >> 4, l16 = lane & 15;
  int g = h >> 2;
  const short* qp = q + (size_t)(b * H_ + h) * T_ * HD_;
  const short* kp = k + (size_t)(b * HKV_ + g) * T_ * HD_;
  const short* vp = v + (size_t)(b * HKV_ + g) * T_ * HD_;
  int q0 = bx * 64 + wave * 16;
  short8 qf0 = *(const short8*)(qp + (q0 + l16) * HD_ + quad * 8);
  short8 qf1 = *(const short8*)(qp + (q0 + l16) * HD_ + 32 + quad * 8);
  floatx4 acc[4] = {};
  float m_r[4] = {-1e30f, -1e30f, -1e30f, -1e30f};
  float l_r[4] = {0.f, 0.f, 0.f, 0.f};
  int qi[4];
#pragma unroll
  for (int r = 0; r < 4; ++r) qi[r] = q0 + quad * 4 + r;
  for (int k0 = 0; k0 < q0 + 16; k0 += 32) {
    floatx4 s0 = {0.f, 0.f, 0.f, 0.f}, s1 = {0.f, 0.f, 0.f, 0.f};
    short8 kf0 = *(const short8*)(kp + (k0 + l16) * HD_ + quad * 8);
    short8 kf0b = *(const short8*)(kp + (k0 + l16) * HD_ + 32 + quad * 8);
    s0 = __builtin_amdgcn_mfma_f32_16x16x32_bf16(qf0, kf0, s0, 0, 0, 0);
    s0 = __builtin_amdgcn_mfma_f32_16x16x32_bf16(qf1, kf0b, s0, 0, 0, 0);
    short8 kf1 = *(const short8*)(kp + (k0 + 16 + l16) * HD_ + quad * 8);
    short8 kf1b = *(const short8*)(kp + (k0 + 16 + l16) * HD_ + 32 + quad * 8);
    s1 = __builtin_amdgcn_mfma_f32_16x16x32_bf16(qf0, kf1, s1, 0, 0, 0);
    s1 = __builtin_amdgcn_mfma_f32_16x16x32_bf16(qf1, kf1b, s1, 0, 0, 0);
    float p0[4], p1[4], mt[4];
#pragma unroll
    for (int r = 0; r < 4; ++r) {
      p0[r] = (k0 + l16 <= qi[r]) ? s0[r] * 0.125f : -1e30f;
      p1[r] = (k0 + 16 + l16 <= qi[r]) ? s1[r] * 0.125f : -1e30f;
      mt[r] = fmaxf(p0[r], p1[r]);
    }
#pragma unroll
    for (int off = 1; off < 16; off <<= 1) {
#pragma unroll
      for (int r = 0; r < 4; ++r) mt[r] = fmaxf(mt[r], __shfl_xor(mt[r], off, 64));
    }
    float alpha[4];
#pragma unroll
    for (int r = 0; r < 4; ++r) {
      float mn = fmaxf(m_r[r], mt[r]);
      alpha[r] = __expf(m_r[r] - mn);
      m_r[r] = mn;
      p0[r] = __expf(p0[r] - mn);
      p1[r] = __expf(p1[r] - mn);
    }
    float rs[4];
#pragma unroll
    for (int r = 0; r < 4; ++r) rs[r] = p0[r] + p1[r];
#pragma unroll
    for (int off = 1; off < 16; off <<= 1) {
#pragma unroll
      for (int r = 0; r < 4; ++r) rs[r] += __shfl_xor(rs[r], off, 64);
    }
#pragma unroll
    for (int r = 0; r < 4; ++r) l_r[r] = l_r[r] * alpha[r] + rs[r];
#pragma unroll
    for (int n = 0; n < 4; ++n)
#pragma unroll
      for (int r = 0; r < 4; ++r) acc[n][r] *= alpha[r];
#pragma unroll
    for (int r = 0; r < 4; ++r) {
      P[wave][(quad * 4 + r) * 40 + l16] = f2b(p0[r]);
      P[wave][(quad * 4 + r) * 40 + 16 + l16] = f2b(p1[r]);
    }
    short8 pf = *(const short8*)(&P[wave][l16 * 40 + quad * 8]);
#pragma unroll
    for (int n = 0; n < 4; ++n) {
      short8 vf;
#pragma unroll
      for (int j = 0; j < 8; ++j)
        vf[j] = vp[(size_t)(k0 + quad * 8 + j) * HD_ + n * 16 + l16];
      acc[n] = __builtin_amdgcn_mfma_f32_16x16x32_bf16(pf, vf, acc[n], 0, 0, 0);
    }
  }
#pragma unroll
  for (int n = 0; n < 4; ++n)
#pragma unroll
    for (int r = 0; r < 4; ++r) {
      int t = q0 + quad * 4 + r;
      y[(size_t)(b * T_ + t) * C_ + h * 64 + n * 16 + l16] = f2b(acc[n][r] / l_r[r]);
    }
}

extern "C" void kernel_launch(void* const* d_in, const int* in_sizes, int n_in,
                              void* d_out, int out_size, void* d_ws, size_t ws_size,
                              hipStream_t stream) {
  const float* x = (const float*)d_in[0];
  const float* cosp = (const float*)d_in[1];
  const float* sinp = (const float*)d_in[2];
  const float* w_attn = (const float*)d_in[3];
  const float* w_proj = (const float*)d_in[4];
  const float* w_gate = (const float*)d_in[5];
  const float* w_up = (const float*)d_in[6];
  const float* w_down = (const float*)d_in[7];
  const float* scale1 = (const float*)d_in[8];
  const float* scale2 = (const float*)d_in[9];
  float* out = (float*)d_out;
  char* ws = (char*)d_ws;

  // workspace layout (bytes), peak 109,051,904 (< 113 MB proven in R1):
  short* S1 = (short*)(ws + 0);           // 23,068,672  wt_gate -> wt_down
  short* S2 = (short*)(ws + 23068672);    // 23,068,672  wt_up
  short* hbuf = (short*)(ws + 46137344);  // 16,777,216  h -> q -> h2
  short* S0 = (short*)(ws + 62914560);    // 12,582,912  wt_attn -> wt_proj
  short* qkv = (short*)(ws + 75497472);   // 25,165,824  qkv -> y
  short* kbuf = (short*)(ws + 100663296); //  4,194,304
  short* vbuf = (short*)(ws + 104857600); //  4,194,304
  short* act = (short*)(ws + 62914560);   // 46,137,344  over S0+qkv+k+v (all dead)

  convt_kernel<<<dim3(3072 / 32, 2048 / 32), 256, 0, stream>>>(w_attn, S0, 2048, 3072);
  rmsnorm_kernel<<<4096, 256, 0, stream>>>(x, scale1, hbuf);
  gemm128_kernel<0><<<dim3(3072 / 128, 4096 / 128), 256, 0, stream>>>(
      hbuf, S0, qkv, nullptr, 4096, 3072, 2048);
  rope_kernel<<<24576, 256, 0, stream>>>(qkv, cosp, sinp, hbuf, kbuf, vbuf);
  attn_kernel<<<dim3(16, 32, 4), 256, 0, stream>>>(hbuf, kbuf, vbuf, qkv);
  convt_kernel<<<dim3(2048 / 32, 2048 / 32), 256, 0, stream>>>(w_proj, S0, 2048, 2048);
  gemm128_kernel<1><<<dim3(2048 / 128, 4096 / 128), 256, 0, stream>>>(
      qkv, S0, out, x, 4096, 2048, 2048);
  rmsnorm_kernel<<<4096, 256, 0, stream>>>(out, scale2, hbuf);
  convt_kernel<<<dim3(5632 / 32, 2048 / 32), 256, 0, stream>>>(w_gate, S1, 2048, 5632);
  convt_kernel<<<dim3(5632 / 32, 2048 / 32), 256, 0, stream>>>(w_up, S2, 2048, 5632);
  gateup_kernel<<<dim3(5632 / 64, 4096 / 128), 256, 0, stream>>>(hbuf, S1, S2, act, 2048);
  convt_kernel<<<dim3(2048 / 32, 5632 / 32), 256, 0, stream>>>(w_down, S1, 5632, 2048);
  gemm128_kernel<1><<<dim3(2048 / 128, 4096 / 128), 256, 0, stream>>>(
      act, S1, out, out, 4096, 2048, 5632);
}

// Round 3
// 889.931 us; speedup vs baseline: 1.5905x; 1.0134x over previous
//
#include <hip/hip_runtime.h>
#include <stdint.h>

#define B_ 4
#define T_ 1024
#define C_ 2048
#define H_ 32
#define HKV_ 8
#define HD_ 64
#define HID_ 5632

typedef __attribute__((ext_vector_type(8))) short short8;
typedef __attribute__((ext_vector_type(4))) float floatx4;

__device__ __forceinline__ float b2f(short s) {
  unsigned u = ((unsigned)(unsigned short)s) << 16;
  return __uint_as_float(u);
}
__device__ __forceinline__ short f2b(float f) {
  unsigned u = __float_as_uint(f);
  u = u + 0x7fffu + ((u >> 16) & 1u);
  return (short)(u >> 16);
}

// async global->LDS, 16B per lane, LDS dest = wave-uniform base + lane*16
#define GL2LDS(gp, lp)                                              \
  __builtin_amdgcn_global_load_lds(                                 \
      (const __attribute__((address_space(1))) void*)(gp),          \
      (__attribute__((address_space(3))) void*)(lp), 16, 0, 0)

// ---------------- weight convert + transpose: W[K][N] fp32 -> Wt[N][K] bf16 ----
__global__ __launch_bounds__(256) void convt_kernel(
    const float* __restrict__ W, short* __restrict__ Wt, int K, int N) {
  __shared__ short t[32][33];
  int n0 = blockIdx.x * 32, k0 = blockIdx.y * 32;
  int tx = threadIdx.x & 31, ty = threadIdx.x >> 5;  // ty 0..7
#pragma unroll
  for (int j = 0; j < 4; ++j)
    t[ty + j * 8][tx] = f2b(W[(size_t)(k0 + ty + j * 8) * N + n0 + tx]);
  __syncthreads();
#pragma unroll
  for (int j = 0; j < 4; ++j)
    Wt[(size_t)(n0 + ty + j * 8) * K + k0 + tx] = t[tx][ty + j * 8];
}

// ---------------- v transpose: vbuf[bg][t][d] bf16 -> vt[bg][d][t] bf16 -------
__global__ __launch_bounds__(256) void vt_kernel(
    const short* __restrict__ vin, short* __restrict__ vout) {
  __shared__ short t[32][33];
  int t0 = blockIdx.x * 32, d0 = blockIdx.y * 32, bg = blockIdx.z;
  int tx = threadIdx.x & 31, ty = threadIdx.x >> 5;
  const short* src = vin + (size_t)bg * T_ * HD_;
  short* dst = vout + (size_t)bg * T_ * HD_;
#pragma unroll
  for (int j = 0; j < 4; ++j)
    t[ty + j * 8][tx] = src[(size_t)(t0 + ty + j * 8) * HD_ + d0 + tx];
  __syncthreads();
#pragma unroll
  for (int j = 0; j < 4; ++j)
    dst[(size_t)(d0 + ty + j * 8) * T_ + t0 + tx] = t[tx][ty + j * 8];
}

// ---------------- RMSNorm: fp32 row -> bf16 row ----------------
__global__ __launch_bounds__(256) void rmsnorm_kernel(
    const float* __restrict__ x, const float* __restrict__ scale,
    short* __restrict__ out) {
  int row = blockIdx.x, tid = threadIdx.x;
  const float4* xr = (const float4*)(x + (size_t)row * C_);
  float4 v0 = xr[tid], v1 = xr[tid + 256];
  float s = v0.x * v0.x + v0.y * v0.y + v0.z * v0.z + v0.w * v0.w +
            v1.x * v1.x + v1.y * v1.y + v1.z * v1.z + v1.w * v1.w;
  for (int off = 32; off > 0; off >>= 1) s += __shfl_down(s, off, 64);
  __shared__ float red[4];
  if ((tid & 63) == 0) red[tid >> 6] = s;
  __syncthreads();
  float tot = red[0] + red[1] + red[2] + red[3];
  float r = rsqrtf(tot * (1.0f / (float)C_) + 1e-6f);
  const float4* sc = (const float4*)scale;
  float4 s0 = sc[tid], s1 = sc[tid + 256];
  short* o = out + (size_t)row * C_;
  o[tid * 4 + 0] = f2b(v0.x * s0.x * r);
  o[tid * 4 + 1] = f2b(v0.y * s0.y * r);
  o[tid * 4 + 2] = f2b(v0.z * s0.z * r);
  o[tid * 4 + 3] = f2b(v0.w * s0.w * r);
  o[1024 + tid * 4 + 0] = f2b(v1.x * s1.x * r);
  o[1024 + tid * 4 + 1] = f2b(v1.y * s1.y * r);
  o[1024 + tid * 4 + 2] = f2b(v1.z * s1.z * r);
  o[1024 + tid * 4 + 3] = f2b(v1.w * s1.w * r);
}

// ---------------- GEMM 128x128, BK=64 -----------------------------------------
// A[M][K] bf16, Bt[N][K] bf16. LDS: 16B chunks, slot(row,kc)=row*8+((kc+row)&7).
// 32 MFMA per barrier pair. EPI 0: bf16 store. EPI 1: fp32 store = resid + acc.
template <int EPI>
__global__ __launch_bounds__(256, 2) void gemm128_kernel(
    const short* __restrict__ A, const short* __restrict__ Bt,
    void* __restrict__ Out, const float* __restrict__ resid,
    int M, int N, int K) {
  __shared__ __align__(16) short smem[16384];
  short* As = smem;          // 1024 slots * 16B
  short* Bs = smem + 8192;
  int tid = threadIdx.x, lane = tid & 63, wave = tid >> 6;
  int quad = lane >> 4, l16 = lane & 15;
  int m0 = blockIdx.y * 128, n0 = blockIdx.x * 128;
  int wm = (wave & 1) * 64, wn = (wave >> 1) * 64;

  const short* ap[4];
  const short* bp[4];
  short* lA[4];
  short* lB[4];
#pragma unroll
  for (int c = 0; c < 4; ++c) {
    int S = wave * 256 + c * 64 + lane;
    int row = S >> 3, kc = ((S & 7) - (row & 7)) & 7;
    ap[c] = A + (size_t)(m0 + row) * K + kc * 8;
    bp[c] = Bt + (size_t)(n0 + row) * K + kc * 8;
    lA[c] = As + (wave * 256 + c * 64) * 8;
    lB[c] = Bs + (wave * 256 + c * 64) * 8;
  }

  int aoff[4], boff[4];
#pragma unroll
  for (int i = 0; i < 4; ++i) {
    int ra = wm + i * 16 + l16;
    aoff[i] = (ra * 8 + ((quad + ra) & 7)) * 8;
    int rb = wn + i * 16 + l16;
    boff[i] = (rb * 8 + ((quad + rb) & 7)) * 8;
  }

  floatx4 acc[4][4] = {};
  for (int k0 = 0; k0 < K; k0 += 64) {
#pragma unroll
    for (int c = 0; c < 4; ++c) {
      GL2LDS(ap[c] + k0, lA[c]);
      GL2LDS(bp[c] + k0, lB[c]);
    }
    __syncthreads();
#pragma unroll
    for (int h = 0; h < 2; ++h) {
      short8 af[4], bf[4];
#pragma unroll
      for (int i = 0; i < 4; ++i) af[i] = *(const short8*)(As + (aoff[i] ^ (h * 32)));
#pragma unroll
      for (int i = 0; i < 4; ++i) bf[i] = *(const short8*)(Bs + (boff[i] ^ (h * 32)));
#pragma unroll
      for (int mi = 0; mi < 4; ++mi)
#pragma unroll
        for (int ni = 0; ni < 4; ++ni)
          acc[mi][ni] = __builtin_amdgcn_mfma_f32_16x16x32_bf16(
              af[mi], bf[ni], acc[mi][ni], 0, 0, 0);
    }
    __syncthreads();
  }
#pragma unroll
  for (int mi = 0; mi < 4; ++mi)
#pragma unroll
    for (int ni = 0; ni < 4; ++ni)
#pragma unroll
      for (int r = 0; r < 4; ++r) {
        int row = m0 + wm + mi * 16 + quad * 4 + r;
        int col = n0 + wn + ni * 16 + l16;
        size_t idx = (size_t)row * N + col;
        float a = acc[mi][ni][r];
        if constexpr (EPI == 0)
          ((short*)Out)[idx] = f2b(a);
        else
          ((float*)Out)[idx] = resid[idx] + a;
      }
}

// ---------------- fused gate+up GEMM (BK=64) with silu-mul epilogue ------------
// B-tile rows 0..63 = Wg[n0..n0+64), 64..127 = Wu. Waves: wm=(w&1)*64, half=w>>1.
__global__ __launch_bounds__(256, 2) void gateup_kernel(
    const short* __restrict__ A, const short* __restrict__ Wg,
    const short* __restrict__ Wu, short* __restrict__ act, int K) {
  __shared__ __align__(16) short smem[16384];
  short* As = smem;
  short* Bs = smem + 8192;
  int tid = threadIdx.x, lane = tid & 63, wave = tid >> 6;
  int quad = lane >> 4, l16 = lane & 15;
  int m0 = blockIdx.y * 128, n0 = blockIdx.x * 64;
  int wm = (wave & 1) * 64, half = wave >> 1;
  int half_stage = wave >> 1;  // B rows staged by this wave: [wave*32,(wave+1)*32)

  const short* ap[4];
  const short* bp[4];
  short* lA[4];
  short* lB[4];
  const short* Bsel = half_stage ? Wu : Wg;
#pragma unroll
  for (int c = 0; c < 4; ++c) {
    int S = wave * 256 + c * 64 + lane;
    int row = S >> 3, kc = ((S & 7) - (row & 7)) & 7;
    ap[c] = A + (size_t)(m0 + row) * K + kc * 8;
    bp[c] = Bsel + (size_t)(n0 + row - half_stage * 64) * K + kc * 8;
    lA[c] = As + (wave * 256 + c * 64) * 8;
    lB[c] = Bs + (wave * 256 + c * 64) * 8;
  }

  int aoff[4], boff[4];
#pragma unroll
  for (int i = 0; i < 4; ++i) {
    int ra = wm + i * 16 + l16;
    aoff[i] = (ra * 8 + ((quad + ra) & 7)) * 8;
    int rb = half * 64 + i * 16 + l16;
    boff[i] = (rb * 8 + ((quad + rb) & 7)) * 8;
  }

  floatx4 acc[4][4] = {};
  for (int k0 = 0; k0 < K; k0 += 64) {
#pragma unroll
    for (int c = 0; c < 4; ++c) {
      GL2LDS(ap[c] + k0, lA[c]);
      GL2LDS(bp[c] + k0, lB[c]);
    }
    __syncthreads();
#pragma unroll
    for (int h = 0; h < 2; ++h) {
      short8 af[4], bf[4];
#pragma unroll
      for (int i = 0; i < 4; ++i) af[i] = *(const short8*)(As + (aoff[i] ^ (h * 32)));
#pragma unroll
      for (int i = 0; i < 4; ++i) bf[i] = *(const short8*)(Bs + (boff[i] ^ (h * 32)));
#pragma unroll
      for (int mi = 0; mi < 4; ++mi)
#pragma unroll
        for (int ni = 0; ni < 4; ++ni)
          acc[mi][ni] = __builtin_amdgcn_mfma_f32_16x16x32_bf16(
              af[mi], bf[ni], acc[mi][ni], 0, 0, 0);
    }
    __syncthreads();
  }
  // epilogue: up waves deposit u (bf16) in LDS [128][64], gate waves combine
  short* Ex = smem;  // 8192 shorts = 128*64
  if (half == 1) {
#pragma unroll
    for (int mi = 0; mi < 4; ++mi)
#pragma unroll
      for (int ni = 0; ni < 4; ++ni)
#pragma unroll
        for (int r = 0; r < 4; ++r)
          Ex[(wm + mi * 16 + quad * 4 + r) * 64 + ni * 16 + l16] =
              f2b(acc[mi][ni][r]);
  }
  __syncthreads();
  if (half == 0) {
#pragma unroll
    for (int mi = 0; mi < 4; ++mi)
#pragma unroll
      for (int ni = 0; ni < 4; ++ni)
#pragma unroll
        for (int r = 0; r < 4; ++r) {
          int row = wm + mi * 16 + quad * 4 + r;
          int col = ni * 16 + l16;
          float u = b2f(Ex[row * 64 + col]);
          float g = acc[mi][ni][r];
          float a = g / (1.0f + __expf(-g)) * u;
          act[(size_t)(m0 + row) * HID_ + n0 + col] = f2b(a);
        }
  }
}

// ---------------- RoPE + QKV split (q pre-scaled by 1/8) ----------------------
__global__ __launch_bounds__(256) void rope_kernel(
    const short* __restrict__ qkv, const float* __restrict__ cosp,
    const float* __restrict__ sinp, short* __restrict__ q,
    short* __restrict__ k, short* __restrict__ v) {
  int idx = blockIdx.x * 256 + threadIdx.x;  // (b,t,head,i)
  int i = idx & 31;
  int rest = idx >> 5;
  int head = rest % 48;
  int rest2 = rest / 48;
  int t = rest2 & 1023;
  int b = rest2 >> 10;
  const short* src = qkv + (size_t)(b * T_ + t) * 3072 + head * 64 + 2 * i;
  float e = b2f(src[0]), o = b2f(src[1]);
  if (head < 32) {
    float c = cosp[t * 32 + i], s = sinp[t * 32 + i];
    short* dst = q + ((size_t)(b * 32 + head) * 1024 + t) * 64 + 2 * i;
    dst[0] = f2b((e * c - o * s) * 0.125f);
    dst[1] = f2b((e * s + o * c) * 0.125f);
  } else if (head < 40) {
    float c = cosp[t * 32 + i], s = sinp[t * 32 + i];
    short* dst = k + ((size_t)(b * 8 + (head - 32)) * 1024 + t) * 64 + 2 * i;
    dst[0] = f2b(e * c - o * s);
    dst[1] = f2b(e * s + o * c);
  } else {
    short* dst = v + ((size_t)(b * 8 + (head - 40)) * 1024 + t) * 64 + 2 * i;
    dst[0] = src[0];
    dst[1] = src[1];
  }
}

// ---------------- Flash attention (GQA, causal), V transposed -----------------
__global__ __launch_bounds__(256) void attn_kernel(
    const short* __restrict__ q, const short* __restrict__ k,
    const short* __restrict__ vt, short* __restrict__ y) {
  __shared__ __align__(16) short P[4][640];
  int bx = blockIdx.x, h = blockIdx.y, b = blockIdx.z;
  int lane = threadIdx.x & 63, wave = threadIdx.x >> 6;
  int quad = lane >> 4, l16 = lane & 15;
  int g = h >> 2;
  const short* qp = q + (size_t)(b * H_ + h) * T_ * HD_;
  const short* kp = k + (size_t)(b * HKV_ + g) * T_ * HD_;
  const short* vp = vt + (size_t)(b * HKV_ + g) * T_ * HD_;  // [d][t]
  int q0 = bx * 64 + wave * 16;
  short8 qf0 = *(const short8*)(qp + (q0 + l16) * HD_ + quad * 8);
  short8 qf1 = *(const short8*)(qp + (q0 + l16) * HD_ + 32 + quad * 8);
  floatx4 acc[4] = {};
  float m_r[4] = {-1e30f, -1e30f, -1e30f, -1e30f};
  float l_r[4] = {0.f, 0.f, 0.f, 0.f};
  int qi[4];
#pragma unroll
  for (int r = 0; r < 4; ++r) qi[r] = q0 + quad * 4 + r;
  for (int k0 = 0; k0 < q0 + 16; k0 += 32) {
    floatx4 s0 = {0.f, 0.f, 0.f, 0.f}, s1 = {0.f, 0.f, 0.f, 0.f};
    short8 kf0 = *(const short8*)(kp + (k0 + l16) * HD_ + quad * 8);
    short8 kf0b = *(const short8*)(kp + (k0 + l16) * HD_ + 32 + quad * 8);
    s0 = __builtin_amdgcn_mfma_f32_16x16x32_bf16(qf0, kf0, s0, 0, 0, 0);
    s0 = __builtin_amdgcn_mfma_f32_16x16x32_bf16(qf1, kf0b, s0, 0, 0, 0);
    short8 kf1 = *(const short8*)(kp + (k0 + 16 + l16) * HD_ + quad * 8);
    short8 kf1b = *(const short8*)(kp + (k0 + 16 + l16) * HD_ + 32 + quad * 8);
    s1 = __builtin_amdgcn_mfma_f32_16x16x32_bf16(qf0, kf1, s1, 0, 0, 0);
    s1 = __builtin_amdgcn_mfma_f32_16x16x32_bf16(qf1, kf1b, s1, 0, 0, 0);
    float p0[4], p1[4], mt[4];
#pragma unroll
    for (int r = 0; r < 4; ++r) {
      p0[r] = (k0 + l16 <= qi[r]) ? s0[r] : -1e30f;
      p1[r] = (k0 + 16 + l16 <= qi[r]) ? s1[r] : -1e30f;
      mt[r] = fmaxf(p0[r], p1[r]);
    }
#pragma unroll
    for (int off = 1; off < 16; off <<= 1) {
#pragma unroll
      for (int r = 0; r < 4; ++r) mt[r] = fmaxf(mt[r], __shfl_xor(mt[r], off, 64));
    }
    float alpha[4];
#pragma unroll
    for (int r = 0; r < 4; ++r) {
      float mn = fmaxf(m_r[r], mt[r]);
      alpha[r] = __expf(m_r[r] - mn);
      m_r[r] = mn;
      p0[r] = __expf(p0[r] - mn);
      p1[r] = __expf(p1[r] - mn);
    }
    float rs[4];
#pragma unroll
    for (int r = 0; r < 4; ++r) rs[r] = p0[r] + p1[r];
#pragma unroll
    for (int off = 1; off < 16; off <<= 1) {
#pragma unroll
      for (int r = 0; r < 4; ++r) rs[r] += __shfl_xor(rs[r], off, 64);
    }
#pragma unroll
    for (int r = 0; r < 4; ++r) l_r[r] = l_r[r] * alpha[r] + rs[r];
#pragma unroll
    for (int n = 0; n < 4; ++n)
#pragma unroll
      for (int r = 0; r < 4; ++r) acc[n][r] *= alpha[r];
#pragma unroll
    for (int r = 0; r < 4; ++r) {
      P[wave][(quad * 4 + r) * 40 + l16] = f2b(p0[r]);
      P[wave][(quad * 4 + r) * 40 + 16 + l16] = f2b(p1[r]);
    }
    short8 pf = *(const short8*)(&P[wave][l16 * 40 + quad * 8]);
#pragma unroll
    for (int n = 0; n < 4; ++n) {
      short8 vf = *(const short8*)(vp + (size_t)(n * 16 + l16) * T_ + k0 + quad * 8);
      acc[n] = __builtin_amdgcn_mfma_f32_16x16x32_bf16(pf, vf, acc[n], 0, 0, 0);
    }
  }
#pragma unroll
  for (int n = 0; n < 4; ++n)
#pragma unroll
    for (int r = 0; r < 4; ++r) {
      int t = q0 + quad * 4 + r;
      y[(size_t)(b * T_ + t) * C_ + h * 64 + n * 16 + l16] = f2b(acc[n][r] / l_r[r]);
    }
}

extern "C" void kernel_launch(void* const* d_in, const int* in_sizes, int n_in,
                              void* d_out, int out_size, void* d_ws, size_t ws_size,
                              hipStream_t stream) {
  const float* x = (const float*)d_in[0];
  const float* cosp = (const float*)d_in[1];
  const float* sinp = (const float*)d_in[2];
  const float* w_attn = (const float*)d_in[3];
  const float* w_proj = (const float*)d_in[4];
  const float* w_gate = (const float*)d_in[5];
  const float* w_up = (const float*)d_in[6];
  const float* w_down = (const float*)d_in[7];
  const float* scale1 = (const float*)d_in[8];
  const float* scale2 = (const float*)d_in[9];
  float* out = (float*)d_out;
  char* ws = (char*)d_ws;

  // workspace layout (bytes), peak 113,246,208 (R1-proven footprint):
  short* S1 = (short*)(ws + 0);            // 23,068,672  wt_gate -> wt_down
  short* S2 = (short*)(ws + 23068672);     // 23,068,672  wt_up
  short* hbuf = (short*)(ws + 46137344);   // 16,777,216  h -> q -> h2
  short* S0 = (short*)(ws + 62914560);     // 12,582,912  wt_attn -> wt_proj
  short* qkv = (short*)(ws + 75497472);    // 25,165,824  qkv -> y
  short* kbuf = (short*)(ws + 100663296);  //  4,194,304
  short* vbuf = (short*)(ws + 104857600);  //  4,194,304
  short* vtbuf = (short*)(ws + 109051904); //  4,194,304  v transposed [bg][d][t]
  short* act = (short*)(ws + 62914560);    // 46,137,344  over S0+qkv+k+v (dead)

  convt_kernel<<<dim3(3072 / 32, 2048 / 32), 256, 0, stream>>>(w_attn, S0, 2048, 3072);
  rmsnorm_kernel<<<4096, 256, 0, stream>>>(x, scale1, hbuf);
  gemm128_kernel<0><<<dim3(3072 / 128, 4096 / 128), 256, 0, stream>>>(
      hbuf, S0, qkv, nullptr, 4096, 3072, 2048);
  rope_kernel<<<24576, 256, 0, stream>>>(qkv, cosp, sinp, hbuf, kbuf, vbuf);
  vt_kernel<<<dim3(32, 2, 32), 256, 0, stream>>>(vbuf, vtbuf);
  attn_kernel<<<dim3(16, 32, 4), 256, 0, stream>>>(hbuf, kbuf, vtbuf, qkv);
  convt_kernel<<<dim3(2048 / 32, 2048 / 32), 256, 0, stream>>>(w_proj, S0, 2048, 2048);
  gemm128_kernel<1><<<dim3(2048 / 128, 4096 / 128), 256, 0, stream>>>(
      qkv, S0, out, x, 4096, 2048, 2048);
  rmsnorm_kernel<<<4096, 256, 0, stream>>>(out, scale2, hbuf);
  convt_kernel<<<dim3(5632 / 32, 2048 / 32), 256, 0, stream>>>(w_gate, S1, 2048, 5632);
  convt_kernel<<<dim3(5632 / 32, 2048 / 32), 256, 0, stream>>>(w_up, S2, 2048, 5632);
  gateup_kernel<<<dim3(5632 / 64, 4096 / 128), 256, 0, stream>>>(hbuf, S1, S2, act, 2048);
  convt_kernel<<<dim3(2048 / 32, 5632 / 32), 256, 0, stream>>>(w_down, S1, 5632, 2048);
  gemm128_kernel<1><<<dim3(2048 / 128, 4096 / 128), 256, 0, stream>>>(
      act, S1, out, out, 4096, 2048, 5632);
}

// Round 4
// 789.403 us; speedup vs baseline: 1.7930x; 1.1273x over previous
//
#include <hip/hip_runtime.h>
#include <stdint.h>

#define B_ 4
#define T_ 1024
#define C_ 2048
#define H_ 32
#define HKV_ 8
#define HD_ 64
#define HID_ 5632

typedef __attribute__((ext_vector_type(8))) short short8;
typedef __attribute__((ext_vector_type(4))) float floatx4;

__device__ __forceinline__ float b2f(short s) {
  unsigned u = ((unsigned)(unsigned short)s) << 16;
  return __uint_as_float(u);
}
__device__ __forceinline__ short f2b(float f) {
  unsigned u = __float_as_uint(f);
  u = u + 0x7fffu + ((u >> 16) & 1u);
  return (short)(u >> 16);
}
__device__ __forceinline__ unsigned pk2(float a, float b) {
  return ((unsigned)(unsigned short)f2b(a)) |
         ((unsigned)(unsigned short)f2b(b) << 16);
}

// async global->LDS, 16B per lane, LDS dest = wave-uniform base + lane*16
#define GL2LDS(gp, lp)                                              \
  __builtin_amdgcn_global_load_lds(                                 \
      (const __attribute__((address_space(1))) void*)(gp),          \
      (__attribute__((address_space(3))) void*)(lp), 16, 0, 0)

// ---------------- weight convert + transpose: W[K][N] fp32 -> Wt[N][K] bf16 ----
// 64x64 tile, pair-packed (2 consecutive k in one uint), uint4 output stores.
__global__ __launch_bounds__(256) void convt_kernel(
    const float* __restrict__ W, short* __restrict__ Wt, int K, int N) {
  __shared__ unsigned u[32][65];
  int n0 = blockIdx.x * 64, k0 = blockIdx.y * 64;
  int tx = threadIdx.x & 63, ty = threadIdx.x >> 6;  // ty 0..3
#pragma unroll
  for (int j = 0; j < 8; ++j) {
    int kpair = ty * 8 + j;  // 0..31
    float lo = W[(size_t)(k0 + 2 * kpair) * N + n0 + tx];
    float hi = W[(size_t)(k0 + 2 * kpair + 1) * N + n0 + tx];
    u[kpair][tx] = pk2(lo, hi);
  }
  __syncthreads();
  int ny = threadIdx.x >> 2, kx = threadIdx.x & 3;
  unsigned vals[8];
#pragma unroll
  for (int i = 0; i < 8; ++i) vals[i] = u[kx * 8 + i][ny];
  uint4* dst = (uint4*)(Wt + (size_t)(n0 + ny) * K + k0 + kx * 16);
  dst[0] = make_uint4(vals[0], vals[1], vals[2], vals[3]);
  dst[1] = make_uint4(vals[4], vals[5], vals[6], vals[7]);
}

// ---------------- v transpose: vbuf[bg][t][d] bf16 -> vt[bg][d][t] bf16 -------
__global__ __launch_bounds__(256) void vt_kernel(
    const short* __restrict__ vin, short* __restrict__ vout) {
  __shared__ short t[32][33];
  int t0 = blockIdx.x * 32, d0 = blockIdx.y * 32, bg = blockIdx.z;
  int tx = threadIdx.x & 31, ty = threadIdx.x >> 5;
  const short* src = vin + (size_t)bg * T_ * HD_;
  short* dst = vout + (size_t)bg * T_ * HD_;
#pragma unroll
  for (int j = 0; j < 4; ++j)
    t[ty + j * 8][tx] = src[(size_t)(t0 + ty + j * 8) * HD_ + d0 + tx];
  __syncthreads();
#pragma unroll
  for (int j = 0; j < 4; ++j)
    dst[(size_t)(d0 + ty + j * 8) * T_ + t0 + tx] = t[tx][ty + j * 8];
}

// ---------------- RMSNorm: fp32 row -> bf16 row ----------------
__global__ __launch_bounds__(256) void rmsnorm_kernel(
    const float* __restrict__ x, const float* __restrict__ scale,
    short* __restrict__ out) {
  int row = blockIdx.x, tid = threadIdx.x;
  const float4* xr = (const float4*)(x + (size_t)row * C_);
  float4 v0 = xr[tid], v1 = xr[tid + 256];
  float s = v0.x * v0.x + v0.y * v0.y + v0.z * v0.z + v0.w * v0.w +
            v1.x * v1.x + v1.y * v1.y + v1.z * v1.z + v1.w * v1.w;
  for (int off = 32; off > 0; off >>= 1) s += __shfl_down(s, off, 64);
  __shared__ float red[4];
  if ((tid & 63) == 0) red[tid >> 6] = s;
  __syncthreads();
  float tot = red[0] + red[1] + red[2] + red[3];
  float r = rsqrtf(tot * (1.0f / (float)C_) + 1e-6f);
  const float4* sc = (const float4*)scale;
  float4 s0 = sc[tid], s1 = sc[tid + 256];
  short* o = out + (size_t)row * C_;
  o[tid * 4 + 0] = f2b(v0.x * s0.x * r);
  o[tid * 4 + 1] = f2b(v0.y * s0.y * r);
  o[tid * 4 + 2] = f2b(v0.z * s0.z * r);
  o[tid * 4 + 3] = f2b(v0.w * s0.w * r);
  o[1024 + tid * 4 + 0] = f2b(v1.x * s1.x * r);
  o[1024 + tid * 4 + 1] = f2b(v1.y * s1.y * r);
  o[1024 + tid * 4 + 2] = f2b(v1.z * s1.z * r);
  o[1024 + tid * 4 + 3] = f2b(v1.w * s1.w * r);
}

// ---------------- GEMM 128x128, BK=64 -----------------------------------------
template <int EPI>
__global__ __launch_bounds__(256, 2) void gemm128_kernel(
    const short* __restrict__ A, const short* __restrict__ Bt,
    void* __restrict__ Out, const float* __restrict__ resid,
    int M, int N, int K) {
  __shared__ __align__(16) short smem[16384];
  short* As = smem;
  short* Bs = smem + 8192;
  int tid = threadIdx.x, lane = tid & 63, wave = tid >> 6;
  int quad = lane >> 4, l16 = lane & 15;
  int m0 = blockIdx.y * 128, n0 = blockIdx.x * 128;
  int wm = (wave & 1) * 64, wn = (wave >> 1) * 64;

  const short* ap[4];
  const short* bp[4];
  short* lA[4];
  short* lB[4];
#pragma unroll
  for (int c = 0; c < 4; ++c) {
    int S = wave * 256 + c * 64 + lane;
    int row = S >> 3, kc = ((S & 7) - (row & 7)) & 7;
    ap[c] = A + (size_t)(m0 + row) * K + kc * 8;
    bp[c] = Bt + (size_t)(n0 + row) * K + kc * 8;
    lA[c] = As + (wave * 256 + c * 64) * 8;
    lB[c] = Bs + (wave * 256 + c * 64) * 8;
  }

  int aoff[4], boff[4];
#pragma unroll
  for (int i = 0; i < 4; ++i) {
    int ra = wm + i * 16 + l16;
    aoff[i] = (ra * 8 + ((quad + ra) & 7)) * 8;
    int rb = wn + i * 16 + l16;
    boff[i] = (rb * 8 + ((quad + rb) & 7)) * 8;
  }

  floatx4 acc[4][4] = {};
  for (int k0 = 0; k0 < K; k0 += 64) {
#pragma unroll
    for (int c = 0; c < 4; ++c) {
      GL2LDS(ap[c] + k0, lA[c]);
      GL2LDS(bp[c] + k0, lB[c]);
    }
    __syncthreads();
#pragma unroll
    for (int h = 0; h < 2; ++h) {
      short8 af[4], bf[4];
#pragma unroll
      for (int i = 0; i < 4; ++i) af[i] = *(const short8*)(As + (aoff[i] ^ (h * 32)));
#pragma unroll
      for (int i = 0; i < 4; ++i) bf[i] = *(const short8*)(Bs + (boff[i] ^ (h * 32)));
#pragma unroll
      for (int mi = 0; mi < 4; ++mi)
#pragma unroll
        for (int ni = 0; ni < 4; ++ni)
          acc[mi][ni] = __builtin_amdgcn_mfma_f32_16x16x32_bf16(
              af[mi], bf[ni], acc[mi][ni], 0, 0, 0);
    }
    __syncthreads();
  }
#pragma unroll
  for (int mi = 0; mi < 4; ++mi)
#pragma unroll
    for (int ni = 0; ni < 4; ++ni)
#pragma unroll
      for (int r = 0; r < 4; ++r) {
        int row = m0 + wm + mi * 16 + quad * 4 + r;
        int col = n0 + wn + ni * 16 + l16;
        size_t idx = (size_t)row * N + col;
        float a = acc[mi][ni][r];
        if constexpr (EPI == 0)
          ((short*)Out)[idx] = f2b(a);
        else
          ((float*)Out)[idx] = resid[idx] + a;
      }
}

// ---------------- fused gate+up GEMM (BK=64) with silu-mul epilogue ------------
__global__ __launch_bounds__(256, 2) void gateup_kernel(
    const short* __restrict__ A, const short* __restrict__ Wg,
    const short* __restrict__ Wu, short* __restrict__ act, int K) {
  __shared__ __align__(16) short smem[16384];
  short* As = smem;
  short* Bs = smem + 8192;
  int tid = threadIdx.x, lane = tid & 63, wave = tid >> 6;
  int quad = lane >> 4, l16 = lane & 15;
  int m0 = blockIdx.y * 128, n0 = blockIdx.x * 64;
  int wm = (wave & 1) * 64, half = wave >> 1;
  int half_stage = wave >> 1;

  const short* ap[4];
  const short* bp[4];
  short* lA[4];
  short* lB[4];
  const short* Bsel = half_stage ? Wu : Wg;
#pragma unroll
  for (int c = 0; c < 4; ++c) {
    int S = wave * 256 + c * 64 + lane;
    int row = S >> 3, kc = ((S & 7) - (row & 7)) & 7;
    ap[c] = A + (size_t)(m0 + row) * K + kc * 8;
    bp[c] = Bsel + (size_t)(n0 + row - half_stage * 64) * K + kc * 8;
    lA[c] = As + (wave * 256 + c * 64) * 8;
    lB[c] = Bs + (wave * 256 + c * 64) * 8;
  }

  int aoff[4], boff[4];
#pragma unroll
  for (int i = 0; i < 4; ++i) {
    int ra = wm + i * 16 + l16;
    aoff[i] = (ra * 8 + ((quad + ra) & 7)) * 8;
    int rb = half * 64 + i * 16 + l16;
    boff[i] = (rb * 8 + ((quad + rb) & 7)) * 8;
  }

  floatx4 acc[4][4] = {};
  for (int k0 = 0; k0 < K; k0 += 64) {
#pragma unroll
    for (int c = 0; c < 4; ++c) {
      GL2LDS(ap[c] + k0, lA[c]);
      GL2LDS(bp[c] + k0, lB[c]);
    }
    __syncthreads();
#pragma unroll
    for (int h = 0; h < 2; ++h) {
      short8 af[4], bf[4];
#pragma unroll
      for (int i = 0; i < 4; ++i) af[i] = *(const short8*)(As + (aoff[i] ^ (h * 32)));
#pragma unroll
      for (int i = 0; i < 4; ++i) bf[i] = *(const short8*)(Bs + (boff[i] ^ (h * 32)));
#pragma unroll
      for (int mi = 0; mi < 4; ++mi)
#pragma unroll
        for (int ni = 0; ni < 4; ++ni)
          acc[mi][ni] = __builtin_amdgcn_mfma_f32_16x16x32_bf16(
              af[mi], bf[ni], acc[mi][ni], 0, 0, 0);
    }
    __syncthreads();
  }
  short* Ex = smem;
  if (half == 1) {
#pragma unroll
    for (int mi = 0; mi < 4; ++mi)
#pragma unroll
      for (int ni = 0; ni < 4; ++ni)
#pragma unroll
        for (int r = 0; r < 4; ++r)
          Ex[(wm + mi * 16 + quad * 4 + r) * 64 + ni * 16 + l16] =
              f2b(acc[mi][ni][r]);
  }
  __syncthreads();
  if (half == 0) {
#pragma unroll
    for (int mi = 0; mi < 4; ++mi)
#pragma unroll
      for (int ni = 0; ni < 4; ++ni)
#pragma unroll
        for (int r = 0; r < 4; ++r) {
          int row = wm + mi * 16 + quad * 4 + r;
          int col = ni * 16 + l16;
          float u = b2f(Ex[row * 64 + col]);
          float g = acc[mi][ni][r];
          float a = g / (1.0f + __expf(-g)) * u;
          act[(size_t)(m0 + row) * HID_ + n0 + col] = f2b(a);
        }
  }
}

// ---------------- RoPE + QKV split (q pre-scaled by 1/8) ----------------------
__global__ __launch_bounds__(256) void rope_kernel(
    const short* __restrict__ qkv, const float* __restrict__ cosp,
    const float* __restrict__ sinp, short* __restrict__ q,
    short* __restrict__ k, short* __restrict__ v) {
  int idx = blockIdx.x * 256 + threadIdx.x;  // (b,t,head,i)
  int i = idx & 31;
  int rest = idx >> 5;
  int head = rest % 48;
  int rest2 = rest / 48;
  int t = rest2 & 1023;
  int b = rest2 >> 10;
  const short* src = qkv + (size_t)(b * T_ + t) * 3072 + head * 64 + 2 * i;
  float e = b2f(src[0]), o = b2f(src[1]);
  if (head < 32) {
    float c = cosp[t * 32 + i], s = sinp[t * 32 + i];
    short* dst = q + ((size_t)(b * 32 + head) * 1024 + t) * 64 + 2 * i;
    dst[0] = f2b((e * c - o * s) * 0.125f);
    dst[1] = f2b((e * s + o * c) * 0.125f);
  } else if (head < 40) {
    float c = cosp[t * 32 + i], s = sinp[t * 32 + i];
    short* dst = k + ((size_t)(b * 8 + (head - 32)) * 1024 + t) * 64 + 2 * i;
    dst[0] = f2b(e * c - o * s);
    dst[1] = f2b(e * s + o * c);
  } else {
    short* dst = v + ((size_t)(b * 8 + (head - 40)) * 1024 + t) * 64 + 2 * i;
    dst[0] = src[0];
    dst[1] = src[1];
  }
}

// ---------------- Flash attention (GQA, causal), S^T/O^T formulation ----------
// S^T = K·Q^T: C col=q=l16, row=key=quad*4+r  -> softmax over keys is in-lane.
// O^T = V^T·P^T: acc col=q=l16 matches per-lane m/l state.
// P via wave-private LDS, XOR-swizzled at 8B granularity (b64 writes, b128 reads).
// Blocks pair q-tiles (bx, 15-bx) -> uniform 17 iterations of 64 keys.
__global__ __launch_bounds__(256) void attn_kernel(
    const short* __restrict__ q, const short* __restrict__ k,
    const short* __restrict__ vt, short* __restrict__ y) {
  __shared__ __align__(16) short P[4][1024];  // per-wave 16 q x 64 key bf16
  int bx = blockIdx.x, h = blockIdx.y, b = blockIdx.z;
  int lane = threadIdx.x & 63, wave = threadIdx.x >> 6;
  int quad = lane >> 4, l16 = lane & 15;
  int g = h >> 2;
  const short* qp = q + (size_t)(b * H_ + h) * T_ * HD_;
  const short* kp = k + (size_t)(b * HKV_ + g) * T_ * HD_;
  const short* vp = vt + (size_t)(b * HKV_ + g) * T_ * HD_;  // [d][t]
  short* Pw = &P[wave][0];
  int sw = (l16 & 7) << 1;  // even xor keeps b128 pairing + 16B alignment
#pragma unroll 1
  for (int half = 0; half < 2; ++half) {
    int tb = half ? (15 - bx) : bx;
    int q0w = tb * 64 + wave * 16;
    int qidx = q0w + l16;
    short8 qf0 = *(const short8*)(qp + (size_t)(q0w + l16) * HD_ + quad * 8);
    short8 qf1 = *(const short8*)(qp + (size_t)(q0w + l16) * HD_ + 32 + quad * 8);
    floatx4 acc[4] = {};
    float m = -1e30f, l = 0.f;
    for (int k0 = 0; k0 <= q0w; k0 += 64) {
      floatx4 st[4];
#pragma unroll
      for (int kt = 0; kt < 4; ++kt) {
        floatx4 z = {0.f, 0.f, 0.f, 0.f};
        const short* kb = kp + (size_t)(k0 + kt * 16 + l16) * HD_;
        short8 kf0 = *(const short8*)(kb + quad * 8);
        short8 kf1 = *(const short8*)(kb + 32 + quad * 8);
        z = __builtin_amdgcn_mfma_f32_16x16x32_bf16(kf0, qf0, z, 0, 0, 0);
        z = __builtin_amdgcn_mfma_f32_16x16x32_bf16(kf1, qf1, z, 0, 0, 0);
        st[kt] = z;
      }
      if (k0 + 64 > q0w) {  // only the diagonal iteration needs the causal mask
#pragma unroll
        for (int kt = 0; kt < 4; ++kt)
#pragma unroll
          for (int r = 0; r < 4; ++r)
            if (k0 + kt * 16 + quad * 4 + r > qidx) st[kt][r] = -1e30f;
      }
      float mloc = -1e30f;
#pragma unroll
      for (int kt = 0; kt < 4; ++kt)
#pragma unroll
        for (int r = 0; r < 4; ++r) mloc = fmaxf(mloc, st[kt][r]);
      mloc = fmaxf(mloc, __shfl_xor(mloc, 16, 64));
      mloc = fmaxf(mloc, __shfl_xor(mloc, 32, 64));
      float mn = fmaxf(m, mloc);
      float alpha = __expf(m - mn);
      m = mn;
      float rsum = 0.f;
#pragma unroll
      for (int kt = 0; kt < 4; ++kt)
#pragma unroll
        for (int r = 0; r < 4; ++r) {
          float p = __expf(st[kt][r] - mn);
          st[kt][r] = p;
          rsum += p;
        }
      rsum += __shfl_xor(rsum, 16, 64);
      rsum += __shfl_xor(rsum, 32, 64);
      l = l * alpha + rsum;
#pragma unroll
      for (int mt = 0; mt < 4; ++mt)
#pragma unroll
        for (int r = 0; r < 4; ++r) acc[mt][r] *= alpha;
      // P^T -> LDS as P[q][key], 4 consecutive keys packed per b64 write
#pragma unroll
      for (int kt = 0; kt < 4; ++kt) {
        int hc = (kt * 4 + quad) ^ sw;
        *(uint2*)(Pw + l16 * 64 + hc * 4) =
            make_uint2(pk2(st[kt][0], st[kt][1]), pk2(st[kt][2], st[kt][3]));
      }
#pragma unroll
      for (int chunk = 0; chunk < 2; ++chunk) {
        int hc = (chunk * 8 + quad * 2) ^ sw;
        short8 pf = *(const short8*)(Pw + l16 * 64 + hc * 4);
#pragma unroll
        for (int mt = 0; mt < 4; ++mt) {
          short8 vf = *(const short8*)(vp + (size_t)(mt * 16 + l16) * T_ +
                                       k0 + chunk * 32 + quad * 8);
          acc[mt] =
              __builtin_amdgcn_mfma_f32_16x16x32_bf16(vf, pf, acc[mt], 0, 0, 0);
        }
      }
    }
    // epilogue: O^T/l -> LDS transpose (wave-private) -> coalesced 16B stores
    float inv = 1.0f / l;
#pragma unroll
    for (int mt = 0; mt < 4; ++mt) {
      int hc = (mt * 4 + quad) ^ sw;  // d chunk = mt*16 + quad*4
      *(uint2*)(Pw + l16 * 64 + hc * 4) =
          make_uint2(pk2(acc[mt][0] * inv, acc[mt][1] * inv),
                     pk2(acc[mt][2] * inv, acc[mt][3] * inv));
    }
    uint2 o0 = *(uint2*)(Pw + l16 * 64 + (((quad * 4 + 0) ^ sw) * 4));
    uint2 o1 = *(uint2*)(Pw + l16 * 64 + (((quad * 4 + 1) ^ sw) * 4));
    uint2 o2 = *(uint2*)(Pw + l16 * 64 + (((quad * 4 + 2) ^ sw) * 4));
    uint2 o3 = *(uint2*)(Pw + l16 * 64 + (((quad * 4 + 3) ^ sw) * 4));
    uint4* dst =
        (uint4*)(y + (size_t)(b * T_ + q0w + l16) * C_ + h * 64 + quad * 16);
    dst[0] = make_uint4(o0.x, o0.y, o1.x, o1.y);
    dst[1] = make_uint4(o2.x, o2.y, o3.x, o3.y);
  }
}

extern "C" void kernel_launch(void* const* d_in, const int* in_sizes, int n_in,
                              void* d_out, int out_size, void* d_ws, size_t ws_size,
                              hipStream_t stream) {
  const float* x = (const float*)d_in[0];
  const float* cosp = (const float*)d_in[1];
  const float* sinp = (const float*)d_in[2];
  const float* w_attn = (const float*)d_in[3];
  const float* w_proj = (const float*)d_in[4];
  const float* w_gate = (const float*)d_in[5];
  const float* w_up = (const float*)d_in[6];
  const float* w_down = (const float*)d_in[7];
  const float* scale1 = (const float*)d_in[8];
  const float* scale2 = (const float*)d_in[9];
  float* out = (float*)d_out;
  char* ws = (char*)d_ws;

  // workspace layout (bytes), peak 113,246,208 (R1-proven footprint):
  short* S1 = (short*)(ws + 0);            // 23,068,672  wt_gate -> wt_down
  short* S2 = (short*)(ws + 23068672);     // 23,068,672  wt_up
  short* hbuf = (short*)(ws + 46137344);   // 16,777,216  h -> q -> h2
  short* S0 = (short*)(ws + 62914560);     // 12,582,912  wt_attn -> wt_proj
  short* qkv = (short*)(ws + 75497472);    // 25,165,824  qkv -> y
  short* kbuf = (short*)(ws + 100663296);  //  4,194,304
  short* vbuf = (short*)(ws + 104857600);  //  4,194,304
  short* vtbuf = (short*)(ws + 109051904); //  4,194,304  v transposed [bg][d][t]
  short* act = (short*)(ws + 62914560);    // 46,137,344  over S0+qkv+k+v (dead)

  convt_kernel<<<dim3(3072 / 64, 2048 / 64), 256, 0, stream>>>(w_attn, S0, 2048, 3072);
  rmsnorm_kernel<<<4096, 256, 0, stream>>>(x, scale1, hbuf);
  gemm128_kernel<0><<<dim3(3072 / 128, 4096 / 128), 256, 0, stream>>>(
      hbuf, S0, qkv, nullptr, 4096, 3072, 2048);
  rope_kernel<<<24576, 256, 0, stream>>>(qkv, cosp, sinp, hbuf, kbuf, vbuf);
  vt_kernel<<<dim3(32, 2, 32), 256, 0, stream>>>(vbuf, vtbuf);
  attn_kernel<<<dim3(8, 32, 4), 256, 0, stream>>>(hbuf, kbuf, vtbuf, qkv);
  convt_kernel<<<dim3(2048 / 64, 2048 / 64), 256, 0, stream>>>(w_proj, S0, 2048, 2048);
  gemm128_kernel<1><<<dim3(2048 / 128, 4096 / 128), 256, 0, stream>>>(
      qkv, S0, out, x, 4096, 2048, 2048);
  rmsnorm_kernel<<<4096, 256, 0, stream>>>(out, scale2, hbuf);
  convt_kernel<<<dim3(5632 / 64, 2048 / 64), 256, 0, stream>>>(w_gate, S1, 2048, 5632);
  convt_kernel<<<dim3(5632 / 64, 2048 / 64), 256, 0, stream>>>(w_up, S2, 2048, 5632);
  gateup_kernel<<<dim3(5632 / 64, 4096 / 128), 256, 0, stream>>>(hbuf, S1, S2, act, 2048);
  convt_kernel<<<dim3(2048 / 64, 5632 / 64), 256, 0, stream>>>(w_down, S1, 5632, 2048);
  gemm128_kernel<1><<<dim3(2048 / 128, 4096 / 128), 256, 0, stream>>>(
      act, S1, out, out, 4096, 2048, 5632);
}